// Round 1
// baseline (4978.041 us; speedup 1.0000x reference)
//
#include <hip/hip_runtime.h>

typedef unsigned short u16;
typedef __attribute__((ext_vector_type(8))) short bf16x8;   // 8 bf16 (4 VGPRs), per guide §3
typedef __attribute__((ext_vector_type(4))) float f32x4;
typedef __attribute__((ext_vector_type(4))) unsigned int uint4v;

#define NLAYER 6
#define D_MODEL 512
#define NHEAD 8
#define DKH 64
#define SEQ 1024
#define BATCH 8
#define FFN 2048
#define MROWS (BATCH * SEQ)  /* 8192 */

__device__ __forceinline__ float b2f(u16 u) {
  union { unsigned u32; float f; } x; x.u32 = ((unsigned)u) << 16; return x.f;
}
__device__ __forceinline__ u16 f2b(float f) {
  union { float f; unsigned u; } x; x.f = f;
  unsigned r = x.u + 0x7FFFu + ((x.u >> 16) & 1u);   // RNE
  return (u16)(r >> 16);
}
__device__ __forceinline__ void unpack8(uint4v w, float* dst) {
#pragma unroll
  for (int q = 0; q < 4; ++q) {
    dst[2 * q]     = b2f((u16)(w[q] & 0xFFFFu));
    dst[2 * q + 1] = b2f((u16)(w[q] >> 16));
  }
}

// ---------- weight transpose + f32->bf16 : src [Z][K][N] f32 -> dst [Z][N][K] bf16 ----------
__global__ __launch_bounds__(256) void transpose_cvt_kernel(
    const float* __restrict__ src, u16* __restrict__ dst, int K, int N)
{
  __shared__ float t[32][33];
  const int z = blockIdx.z;
  src += (size_t)z * K * N;
  dst += (size_t)z * K * N;
  const int n0 = blockIdx.x * 32, k0 = blockIdx.y * 32;
  const int tx = threadIdx.x, ty = threadIdx.y;  // 32 x 8
#pragma unroll
  for (int i = 0; i < 32; i += 8)
    t[ty + i][tx] = src[(size_t)(k0 + ty + i) * N + n0 + tx];
  __syncthreads();
#pragma unroll
  for (int i = 0; i < 32; i += 8)
    dst[(size_t)(n0 + ty + i) * K + k0 + tx] = f2b(t[tx][ty + i]);
}

// ---------- embedding: h = emb[ids]*sqrt(D) + pe[s] ----------
__global__ __launch_bounds__(256) void embed_kernel(
    const int* __restrict__ ids, const float* __restrict__ emb,
    const float* __restrict__ pe, float* __restrict__ Hf, u16* __restrict__ Hb)
{
  const int row = blockIdx.x;          // b*SEQ + s
  const int s = row & (SEQ - 1);
  const int id = ids[row];
  const int tid = threadIdx.x;
#pragma unroll
  for (int u = 0; u < 2; ++u) {
    const int d = tid + u * 256;
    float v = emb[(size_t)id * D_MODEL + d] * 22.62741699796952f + pe[(size_t)s * D_MODEL + d];
    Hf[(size_t)row * D_MODEL + d] = v;
    Hb[(size_t)row * D_MODEL + d] = f2b(v);
  }
}

// ---------- bf16 MFMA GEMM: C[M,N] = A[M,K] @ Bt[N,K]^T + bias ----------
// 128x128 tile, BK=32, 4 waves each 64x64 via 4x4 mfma_f32_16x16x32_bf16.
template<bool RELU, bool OUTF, bool OUTB>
__global__ __launch_bounds__(256) void gemm_kernel(
    const u16* __restrict__ A, const u16* __restrict__ Bt,
    const float* __restrict__ bias,
    float* __restrict__ Cf, u16* __restrict__ Cb,
    int M, int N, int K)
{
  __shared__ __align__(16) u16 As[128 * 32];
  __shared__ __align__(16) u16 Bs[128 * 32];
  const int tid = threadIdx.x;
  const int bm = blockIdx.x * 128, bn = blockIdx.y * 128;
  const int wave = tid >> 6, lane = tid & 63;
  const int lm = lane & 15, quad = lane >> 4;
  const int wm = (wave & 1) * 64, wn = (wave >> 1) * 64;
  const int r0 = tid >> 2;            // 0..63
  const int c0 = (tid & 3) * 8;       // 0,8,16,24

  const u16* Ap = A  + (size_t)(bm + r0) * K + c0;
  const u16* Bp = Bt + (size_t)(bn + r0) * K + c0;

  f32x4 acc[4][4] = {};

  uint4v a0 = *(const uint4v*)Ap;
  uint4v a1 = *(const uint4v*)(Ap + (size_t)64 * K);
  uint4v b0 = *(const uint4v*)Bp;
  uint4v b1 = *(const uint4v*)(Bp + (size_t)64 * K);

  for (int kk = 0; kk < K; kk += 32) {
    __syncthreads();
    *(uint4v*)&As[r0 * 32 + c0]        = a0;
    *(uint4v*)&As[(r0 + 64) * 32 + c0] = a1;
    *(uint4v*)&Bs[r0 * 32 + c0]        = b0;
    *(uint4v*)&Bs[(r0 + 64) * 32 + c0] = b1;
    __syncthreads();
    if (kk + 32 < K) {   // register prefetch of next K-tile, overlaps MFMA below
      a0 = *(const uint4v*)(Ap + kk + 32);
      a1 = *(const uint4v*)(Ap + kk + 32 + (size_t)64 * K);
      b0 = *(const uint4v*)(Bp + kk + 32);
      b1 = *(const uint4v*)(Bp + kk + 32 + (size_t)64 * K);
    }
    bf16x8 af[4], bg[4];
#pragma unroll
    for (int i = 0; i < 4; ++i)
      af[i] = *(const bf16x8*)&As[(wm + i * 16 + lm) * 32 + quad * 8];
#pragma unroll
    for (int j = 0; j < 4; ++j)
      bg[j] = *(const bf16x8*)&Bs[(wn + j * 16 + lm) * 32 + quad * 8];
#pragma unroll
    for (int i = 0; i < 4; ++i)
#pragma unroll
      for (int j = 0; j < 4; ++j)
        acc[i][j] = __builtin_amdgcn_mfma_f32_16x16x32_bf16(af[i], bg[j], acc[i][j], 0, 0, 0);
  }

  // epilogue: D row = quad*4+reg, col = lm (guide §3, m89/m91-verified)
  const int mbase = bm + wm + quad * 4;
  const int nbase = bn + wn + lm;
#pragma unroll
  for (int i = 0; i < 4; ++i) {
#pragma unroll
    for (int j = 0; j < 4; ++j) {
      const int n = nbase + j * 16;
      const float bv = bias[n];
#pragma unroll
      for (int r = 0; r < 4; ++r) {
        const int m = mbase + i * 16 + r;
        float v = acc[i][j][r] + bv;
        if (RELU) v = fmaxf(v, 0.f);
        if (OUTF) Cf[(size_t)m * N + n] = v;
        if (OUTB) Cb[(size_t)m * N + n] = f2b(v);
      }
    }
  }
}

// ---------- flash-style attention with the reference's anti-causal mask (keep j > i) ----------
// one wave per query row; row S-1 is fully masked -> softmax uniform over ALL keys.
__global__ __launch_bounds__(256) void attn_kernel(
    const u16* __restrict__ Q, const u16* __restrict__ Kb,
    const u16* __restrict__ Vb, u16* __restrict__ O)
{
  __shared__ float Ks[64][65];   // +1 pad: (lane+d)%32 banks -> 2-way (free)
  __shared__ float Vs[64][65];
  __shared__ float qs[4][64];
  __shared__ float ps[4][64];
  const int tid = threadIdx.x;
  const int wave = tid >> 6, lane = tid & 63;
  const int b = blockIdx.z, h = blockIdx.y;
  const int base = blockIdx.x * 4;
  const int i = base + wave;
  const bool last = (i == SEQ - 1);

  qs[wave][lane] = b2f(Q[(size_t)(b * SEQ + i) * D_MODEL + h * DKH + lane]);

  float m_run = -1e30f, l_run = 0.f, o_acc = 0.f;   // lane = output dim d
  // block-uniform tile start (waves stay in lockstep so __syncthreads is safe);
  // last block starts at 0 to cover the uniform row.
  const int t0 = (base == SEQ - 4) ? 0 : ((base + 1) >> 6);
  const int rr = tid >> 2, cc = (tid & 3) * 16;

  for (int jt = t0; jt < SEQ / 64; ++jt) {
    __syncthreads();   // previous iteration's reads done before overwrite
    {
      const size_t goff = (size_t)(b * SEQ + jt * 64 + rr) * D_MODEL + h * DKH + cc;
      uint4v k0 = *(const uint4v*)(Kb + goff);
      uint4v k1 = *(const uint4v*)(Kb + goff + 8);
      uint4v v0 = *(const uint4v*)(Vb + goff);
      uint4v v1 = *(const uint4v*)(Vb + goff + 8);
      unpack8(k0, &Ks[rr][cc]);
      unpack8(k1, &Ks[rr][cc + 8]);
      unpack8(v0, &Vs[rr][cc]);
      unpack8(v1, &Vs[rr][cc + 8]);
    }
    __syncthreads();

    float s = 0.f;                      // lane = key j within tile
#pragma unroll 16
    for (int d = 0; d < 64; ++d) s += qs[wave][d] * Ks[lane][d];
    s *= 0.125f;                        // 1/sqrt(DK)
    const int j = jt * 64 + lane;
    const bool valid = last || (j > i); // reference keeps strictly j > i
    if (last) s = 0.f;                  // all -1e9 == all equal -> uniform softmax
    if (!valid) s = -1e30f;

    float mt = s;
#pragma unroll
    for (int o = 32; o > 0; o >>= 1) mt = fmaxf(mt, __shfl_xor(mt, o, 64));
    const float m_new = fmaxf(m_run, mt);
    const float alpha = expf(m_run - m_new);
    const float p = valid ? expf(s - m_new) : 0.f;
    float pt = p;
#pragma unroll
    for (int o = 32; o > 0; o >>= 1) pt += __shfl_xor(pt, o, 64);
    l_run = l_run * alpha + pt;
    o_acc *= alpha;
    m_run = m_new;
    ps[wave][lane] = p;
    __syncthreads();                    // cross-lane p visibility (lockstep-safe)
#pragma unroll 16
    for (int l2 = 0; l2 < 64; ++l2) o_acc += ps[wave][l2] * Vs[l2][lane];
  }
  O[(size_t)(b * SEQ + i) * D_MODEL + h * DKH + lane] = f2b(o_acc / l_run);
}

// ---------- fused residual add + LayerNorm; writes f32 (residual) + bf16 (GEMM input) ----------
__global__ __launch_bounds__(256) void add_ln_kernel(
    const float* __restrict__ Hin, const float* __restrict__ T,
    const float* __restrict__ g, const float* __restrict__ bta,
    float* __restrict__ Hout, u16* __restrict__ Hb)
{
  __shared__ float red[8];
  const int row = blockIdx.x, tid = threadIdx.x;
  const int wave = tid >> 6, lane = tid & 63;
  const size_t base = (size_t)row * D_MODEL;
  const float x0 = Hin[base + tid] + T[base + tid];
  const float x1 = Hin[base + tid + 256] + T[base + tid + 256];
  float s = x0 + x1;
#pragma unroll
  for (int o = 32; o > 0; o >>= 1) s += __shfl_xor(s, o, 64);
  if (lane == 0) red[wave] = s;
  __syncthreads();
  const float mu = (red[0] + red[1] + red[2] + red[3]) * (1.f / 512.f);
  const float d0 = x0 - mu, d1 = x1 - mu;
  float v = d0 * d0 + d1 * d1;
#pragma unroll
  for (int o = 32; o > 0; o >>= 1) v += __shfl_xor(v, o, 64);
  if (lane == 0) red[4 + wave] = v;
  __syncthreads();
  const float var = (red[4] + red[5] + red[6] + red[7]) * (1.f / 512.f);
  const float rs = rsqrtf(var + 1e-5f);
  const float y0 = d0 * rs * g[tid] + bta[tid];
  const float y1 = d1 * rs * g[tid + 256] + bta[tid + 256];
  Hout[base + tid] = y0;
  Hout[base + tid + 256] = y1;
  Hb[base + tid] = f2b(y0);
  Hb[base + tid + 256] = f2b(y1);
}

extern "C" void kernel_launch(void* const* d_in, const int* in_sizes, int n_in,
                              void* d_out, int out_size, void* d_ws, size_t ws_size,
                              hipStream_t stream) {
  (void)in_sizes; (void)n_in; (void)out_size; (void)ws_size;
  const int*   ids  = (const int*)  d_in[0];
  const float* emb  = (const float*)d_in[1];
  const float* pe   = (const float*)d_in[2];
  const float* Wq   = (const float*)d_in[3];
  const float* bq   = (const float*)d_in[4];
  const float* Wk   = (const float*)d_in[5];
  const float* bk   = (const float*)d_in[6];
  const float* Wv   = (const float*)d_in[7];
  const float* bv   = (const float*)d_in[8];
  const float* Wo   = (const float*)d_in[9];
  const float* bo   = (const float*)d_in[10];
  const float* g1   = (const float*)d_in[11];
  const float* be1  = (const float*)d_in[12];
  const float* W1   = (const float*)d_in[13];
  const float* b1   = (const float*)d_in[14];
  const float* W2   = (const float*)d_in[15];
  const float* b2   = (const float*)d_in[16];
  const float* g2   = (const float*)d_in[17];
  const float* be2  = (const float*)d_in[18];
  const float* Wout = (const float*)d_in[19];
  const float* bout = (const float*)d_in[20];
  float* out = (float*)d_out;

  char* wsp = (char*)d_ws;
  auto alloc = [&](size_t bytes) -> char* {
    char* p = wsp; wsp += (bytes + 255) & ~(size_t)255; return p;
  };
  const size_t dd = (size_t)D_MODEL * D_MODEL;          // 262144
  const size_t df = (size_t)D_MODEL * FFN;              // 1048576
  u16* wq_t  = (u16*)alloc(NLAYER * dd * 2);
  u16* wk_t  = (u16*)alloc(NLAYER * dd * 2);
  u16* wv_t  = (u16*)alloc(NLAYER * dd * 2);
  u16* wo_t  = (u16*)alloc(NLAYER * dd * 2);
  u16* w1_t  = (u16*)alloc(NLAYER * df * 2);
  u16* w2_t  = (u16*)alloc(NLAYER * df * 2);
  u16* wout_t= (u16*)alloc(dd * 2);
  float* hf  = (float*)alloc((size_t)MROWS * D_MODEL * 4);
  u16*   hb  = (u16*)  alloc((size_t)MROWS * D_MODEL * 2);
  u16*   qb  = (u16*)  alloc((size_t)MROWS * D_MODEL * 2);  // 8 MB, no pad (mult of 256)
  u16*   kb  = (u16*)  alloc((size_t)MROWS * D_MODEL * 2);
  u16*   vb  = (u16*)  alloc((size_t)MROWS * D_MODEL * 2);
  u16*   ob  = (u16*)  alloc((size_t)MROWS * D_MODEL * 2);
  float* tf  = (float*)alloc((size_t)MROWS * D_MODEL * 4);
  u16*   mid = qb;  // FFN mid [8192,2048] bf16 aliases the (dead-by-then) q/k/v/o region

  dim3 tb(32, 8);
  transpose_cvt_kernel<<<dim3(16, 16, NLAYER), tb, 0, stream>>>(Wq, wq_t, 512, 512);
  transpose_cvt_kernel<<<dim3(16, 16, NLAYER), tb, 0, stream>>>(Wk, wk_t, 512, 512);
  transpose_cvt_kernel<<<dim3(16, 16, NLAYER), tb, 0, stream>>>(Wv, wv_t, 512, 512);
  transpose_cvt_kernel<<<dim3(16, 16, NLAYER), tb, 0, stream>>>(Wo, wo_t, 512, 512);
  transpose_cvt_kernel<<<dim3(64, 16, NLAYER), tb, 0, stream>>>(W1, w1_t, 512, 2048);
  transpose_cvt_kernel<<<dim3(16, 64, NLAYER), tb, 0, stream>>>(W2, w2_t, 2048, 512);
  transpose_cvt_kernel<<<dim3(16, 16, 1),      tb, 0, stream>>>(Wout, wout_t, 512, 512);

  embed_kernel<<<MROWS, 256, 0, stream>>>(ids, emb, pe, hf, hb);

  for (int l = 0; l < NLAYER; ++l) {
    gemm_kernel<false, false, true><<<dim3(64, 4), 256, 0, stream>>>(
        hb, wq_t + l * dd, bq + l * 512, nullptr, qb, MROWS, 512, 512);
    gemm_kernel<false, false, true><<<dim3(64, 4), 256, 0, stream>>>(
        hb, wk_t + l * dd, bk + l * 512, nullptr, kb, MROWS, 512, 512);
    gemm_kernel<false, false, true><<<dim3(64, 4), 256, 0, stream>>>(
        hb, wv_t + l * dd, bv + l * 512, nullptr, vb, MROWS, 512, 512);
    attn_kernel<<<dim3(SEQ / 4, NHEAD, BATCH), 256, 0, stream>>>(qb, kb, vb, ob);
    gemm_kernel<false, true, false><<<dim3(64, 4), 256, 0, stream>>>(
        ob, wo_t + l * dd, bo + l * 512, tf, nullptr, MROWS, 512, 512);
    add_ln_kernel<<<MROWS, 256, 0, stream>>>(hf, tf, g1 + l * 512, be1 + l * 512, hf, hb);
    gemm_kernel<true, false, true><<<dim3(64, 16), 256, 0, stream>>>(
        hb, w1_t + l * df, b1 + l * 2048, nullptr, mid, MROWS, 2048, 512);
    gemm_kernel<false, true, false><<<dim3(64, 4), 256, 0, stream>>>(
        mid, w2_t + l * df, b2 + l * 512, tf, nullptr, MROWS, 512, 2048);
    add_ln_kernel<<<MROWS, 256, 0, stream>>>(hf, tf, g2 + l * 512, be2 + l * 512, hf, hb);
  }
  gemm_kernel<false, true, false><<<dim3(64, 4), 256, 0, stream>>>(
      hb, wout_t, bout, out, nullptr, MROWS, 512, 512);
}

// Round 2
// 1508.635 us; speedup vs baseline: 3.2997x; 3.2997x over previous
//
#include <hip/hip_runtime.h>

typedef unsigned short u16;
typedef __attribute__((ext_vector_type(8))) short bf16x8;   // 8 bf16 (4 VGPRs), per guide §3
typedef __attribute__((ext_vector_type(4))) float f32x4;
typedef __attribute__((ext_vector_type(4))) unsigned int uint4v;

#define NLAYER 6
#define D_MODEL 512
#define NHEAD 8
#define DKH 64
#define SEQ 1024
#define BATCH 8
#define FFN 2048
#define MROWS (BATCH * SEQ)  /* 8192 */
#define SCALE_LOG2E 0.18033688011112042f  /* (1/sqrt(64)) * log2(e) */

__device__ __forceinline__ float b2f(u16 u) {
  union { unsigned u32; float f; } x; x.u32 = ((unsigned)u) << 16; return x.f;
}
__device__ __forceinline__ u16 f2b(float f) {
  union { float f; unsigned u; } x; x.f = f;
  unsigned r = x.u + 0x7FFFu + ((x.u >> 16) & 1u);   // RNE
  return (u16)(r >> 16);
}

// ---------- weight transpose + f32->bf16 : src [Z][K][N] f32 -> dst [Z][N][K] bf16 ----------
__global__ __launch_bounds__(256) void transpose_cvt_kernel(
    const float* __restrict__ src, u16* __restrict__ dst, int K, int N)
{
  __shared__ float t[32][33];
  const int z = blockIdx.z;
  src += (size_t)z * K * N;
  dst += (size_t)z * K * N;
  const int n0 = blockIdx.x * 32, k0 = blockIdx.y * 32;
  const int tx = threadIdx.x, ty = threadIdx.y;  // 32 x 8
#pragma unroll
  for (int i = 0; i < 32; i += 8)
    t[ty + i][tx] = src[(size_t)(k0 + ty + i) * N + n0 + tx];
  __syncthreads();
#pragma unroll
  for (int i = 0; i < 32; i += 8)
    dst[(size_t)(n0 + ty + i) * K + k0 + tx] = f2b(t[tx][ty + i]);
}

// ---------- embedding: h = emb[ids]*sqrt(D) + pe[s] ----------
__global__ __launch_bounds__(256) void embed_kernel(
    const int* __restrict__ ids, const float* __restrict__ emb,
    const float* __restrict__ pe, float* __restrict__ Hf, u16* __restrict__ Hb)
{
  const int row = blockIdx.x;          // b*SEQ + s
  const int s = row & (SEQ - 1);
  const int id = ids[row];
  const int tid = threadIdx.x;
#pragma unroll
  for (int u = 0; u < 2; ++u) {
    const int d = tid + u * 256;
    float v = emb[(size_t)id * D_MODEL + d] * 22.62741699796952f + pe[(size_t)s * D_MODEL + d];
    Hf[(size_t)row * D_MODEL + d] = v;
    Hb[(size_t)row * D_MODEL + d] = f2b(v);
  }
}

// ---------- bf16 MFMA GEMM: C[M,N] = A[M,K] @ Bt[N,K]^T + bias ----------
// 128x128 tile, BK=32, 4 waves each 64x64 via 4x4 mfma_f32_16x16x32_bf16.
template<bool RELU, bool OUTF, bool OUTB>
__global__ __launch_bounds__(256) void gemm_kernel(
    const u16* __restrict__ A, const u16* __restrict__ Bt,
    const float* __restrict__ bias,
    float* __restrict__ Cf, u16* __restrict__ Cb,
    int M, int N, int K)
{
  __shared__ __align__(16) u16 As[128 * 32];
  __shared__ __align__(16) u16 Bs[128 * 32];
  const int tid = threadIdx.x;
  const int bm = blockIdx.x * 128, bn = blockIdx.y * 128;
  const int wave = tid >> 6, lane = tid & 63;
  const int lm = lane & 15, quad = lane >> 4;
  const int wm = (wave & 1) * 64, wn = (wave >> 1) * 64;
  const int r0 = tid >> 2;            // 0..63
  const int c0 = (tid & 3) * 8;       // 0,8,16,24

  const u16* Ap = A  + (size_t)(bm + r0) * K + c0;
  const u16* Bp = Bt + (size_t)(bn + r0) * K + c0;

  f32x4 acc[4][4] = {};

  uint4v a0 = *(const uint4v*)Ap;
  uint4v a1 = *(const uint4v*)(Ap + (size_t)64 * K);
  uint4v b0 = *(const uint4v*)Bp;
  uint4v b1 = *(const uint4v*)(Bp + (size_t)64 * K);

  for (int kk = 0; kk < K; kk += 32) {
    __syncthreads();
    *(uint4v*)&As[r0 * 32 + c0]        = a0;
    *(uint4v*)&As[(r0 + 64) * 32 + c0] = a1;
    *(uint4v*)&Bs[r0 * 32 + c0]        = b0;
    *(uint4v*)&Bs[(r0 + 64) * 32 + c0] = b1;
    __syncthreads();
    if (kk + 32 < K) {   // register prefetch of next K-tile, overlaps MFMA below
      a0 = *(const uint4v*)(Ap + kk + 32);
      a1 = *(const uint4v*)(Ap + kk + 32 + (size_t)64 * K);
      b0 = *(const uint4v*)(Bp + kk + 32);
      b1 = *(const uint4v*)(Bp + kk + 32 + (size_t)64 * K);
    }
    bf16x8 af[4], bg[4];
#pragma unroll
    for (int i = 0; i < 4; ++i)
      af[i] = *(const bf16x8*)&As[(wm + i * 16 + lm) * 32 + quad * 8];
#pragma unroll
    for (int j = 0; j < 4; ++j)
      bg[j] = *(const bf16x8*)&Bs[(wn + j * 16 + lm) * 32 + quad * 8];
#pragma unroll
    for (int i = 0; i < 4; ++i)
#pragma unroll
      for (int j = 0; j < 4; ++j)
        acc[i][j] = __builtin_amdgcn_mfma_f32_16x16x32_bf16(af[i], bg[j], acc[i][j], 0, 0, 0);
  }

  // epilogue: D row = quad*4+reg, col = lm (guide §3, m89/m91-verified)
  const int mbase = bm + wm + quad * 4;
  const int nbase = bn + wn + lm;
#pragma unroll
  for (int i = 0; i < 4; ++i) {
#pragma unroll
    for (int j = 0; j < 4; ++j) {
      const int n = nbase + j * 16;
      const float bv = bias[n];
#pragma unroll
      for (int r = 0; r < 4; ++r) {
        const int m = mbase + i * 16 + r;
        float v = acc[i][j][r] + bv;
        if (RELU) v = fmaxf(v, 0.f);
        if (OUTF) Cf[(size_t)m * N + n] = v;
        if (OUTB) Cb[(size_t)m * N + n] = f2b(v);
      }
    }
  }
}

// ---------- MFMA flash attention, anti-causal mask (keep strictly j > i) ----------
// Block = 4 waves = 64 q-rows of one (b,h); wave owns 16 q-rows.
// K staged Ks[j][d], V staged transposed Vs[d][j]; both bf16 with XOR chunk
// swizzle: elem (row, col) lives at row*64 + (((col>>3) ^ (row&7))<<3) + (col&7)
// -> 16B-aligned b128 frag reads with even 8-dwords/bank spread.
// Row S-1 (fully masked -> uniform softmax) is fixed up by vmean kernels after.
__global__ __launch_bounds__(256) void attn_mfma_kernel(
    const u16* __restrict__ Q, const u16* __restrict__ Kb,
    const u16* __restrict__ Vb, u16* __restrict__ O)
{
  __shared__ __align__(16) u16 Ks[64 * 64];
  __shared__ __align__(16) u16 Vs[64 * 64];
  __shared__ __align__(16) u16 Ps[4 * 16 * 64];
  const int tid = threadIdx.x;
  const int wave = tid >> 6, lane = tid & 63;
  const int quad = lane >> 4, l15 = lane & 15, l7 = lane & 7;
  const int b = blockIdx.z, h = blockIdx.y, t = blockIdx.x;   // q-tile
  const int qbase = t * 64;

  // Q A-frags (held in registers for the whole kernel): m=l15 -> q row, k=quad*8(+32)
  const int qrow = qbase + wave * 16 + l15;
  const u16* qp = Q + (size_t)(b * SEQ + qrow) * D_MODEL + h * DKH + quad * 8;
  const bf16x8 qf0 = *(const bf16x8*)qp;
  const bf16x8 qf1 = *(const bf16x8*)(qp + 32);

  f32x4 oacc[4] = {};                 // D-layout: row=quad*4+r, col d = nt*16+l15
  float m_run[4], l_run[4];
#pragma unroll
  for (int r = 0; r < 4; ++r) { m_run[r] = -3.0e38f; l_run[r] = 0.f; }

  const int kr = tid >> 2;            // staged row 0..63 (key index j)
  const int kc = (tid & 3) * 16;      // staged dim start {0,16,32,48}
  const size_t kvbase = (size_t)(b * SEQ) * D_MODEL + h * DKH;
  u16* psw = Ps + wave * (16 * 64);

  for (int jt = t; jt < SEQ / 64; ++jt) {
    __syncthreads();                  // prior iter's frag reads done before restage
    {
      const u16* kp = Kb + kvbase + (size_t)(jt * 64 + kr) * D_MODEL + kc;
      uint4v k0 = *(const uint4v*)kp;
      uint4v k1 = *(const uint4v*)(kp + 8);
      const int r7 = kr & 7;
      *(uint4v*)&Ks[kr * 64 + ((((kc >> 3) + 0) ^ r7) << 3)] = k0;
      *(uint4v*)&Ks[kr * 64 + ((((kc >> 3) + 1) ^ r7) << 3)] = k1;
      const u16* vp = Vb + kvbase + (size_t)(jt * 64 + kr) * D_MODEL + kc;
      uint4v v0 = *(const uint4v*)vp;
      uint4v v1 = *(const uint4v*)(vp + 8);
      const int jhi = kr >> 3, jlo = kr & 7;   // V transpose: (d, j=kr)
#pragma unroll
      for (int q = 0; q < 8; ++q) {
        int d = kc + q;
        Vs[d * 64 + ((jhi ^ (d & 7)) << 3) + jlo] =
            (u16)((q & 1) ? (v0[q >> 1] >> 16) : (v0[q >> 1] & 0xFFFFu));
        d = kc + 8 + q;
        Vs[d * 64 + ((jhi ^ (d & 7)) << 3) + jlo] =
            (u16)((q & 1) ? (v1[q >> 1] >> 16) : (v1[q >> 1] & 0xFFFFu));
      }
    }
    __syncthreads();

    // S = Q K^T : per wave 16q x 64key as 4 n-tiles x 2 k-steps
    f32x4 sacc[4] = {};
#pragma unroll
    for (int nt = 0; nt < 4; ++nt) {
      const int key = nt * 16 + l15;
      const int k7 = key & 7;
      bf16x8 kb0 = *(const bf16x8*)&Ks[key * 64 + (((quad + 0) ^ k7) << 3)];
      bf16x8 kb1 = *(const bf16x8*)&Ks[key * 64 + (((quad + 4) ^ k7) << 3)];
      sacc[nt] = __builtin_amdgcn_mfma_f32_16x16x32_bf16(qf0, kb0, sacc[nt], 0, 0, 0);
      sacc[nt] = __builtin_amdgcn_mfma_f32_16x16x32_bf16(qf1, kb1, sacc[nt], 0, 0, 0);
    }

    // scale into exp2 domain + mask (diagonal tile only; wave-uniform branch)
    if (jt == t) {
#pragma unroll
      for (int nt = 0; nt < 4; ++nt)
#pragma unroll
        for (int r = 0; r < 4; ++r) {
          const int i = qbase + wave * 16 + quad * 4 + r;
          const int j = jt * 64 + nt * 16 + l15;
          sacc[nt][r] = (j > i) ? sacc[nt][r] * SCALE_LOG2E : -3.0e38f;
        }
    } else {
#pragma unroll
      for (int nt = 0; nt < 4; ++nt)
#pragma unroll
        for (int r = 0; r < 4; ++r) sacc[nt][r] *= SCALE_LOG2E;
    }

    // per-row (quad-group) online-softmax stats
    float tmax[4];
#pragma unroll
    for (int r = 0; r < 4; ++r)
      tmax[r] = fmaxf(fmaxf(sacc[0][r], sacc[1][r]), fmaxf(sacc[2][r], sacc[3][r]));
#pragma unroll
    for (int o = 1; o < 16; o <<= 1)
#pragma unroll
      for (int r = 0; r < 4; ++r) tmax[r] = fmaxf(tmax[r], __shfl_xor(tmax[r], o, 16));
    float alpha[4], m_new[4], tsum[4];
#pragma unroll
    for (int r = 0; r < 4; ++r) {
      m_new[r] = fmaxf(m_run[r], tmax[r]);
      alpha[r] = exp2f(m_run[r] - m_new[r]);
      m_run[r] = m_new[r];
      tsum[r] = 0.f;
    }
    // p = exp2(s - m_new); write to Ps (C-layout -> A-layout via LDS, guide §B)
#pragma unroll
    for (int nt = 0; nt < 4; ++nt)
#pragma unroll
      for (int r = 0; r < 4; ++r) {
        const float p = exp2f(sacc[nt][r] - m_new[r]);  // masked: exp2(-3e38-m)=0
        tsum[r] += p;
        const int qr = quad * 4 + r;
        const int j = nt * 16 + l15;
        psw[qr * 64 + (((j >> 3) ^ (qr & 7)) << 3) + (j & 7)] = f2b(p);
      }
#pragma unroll
    for (int o = 1; o < 16; o <<= 1)
#pragma unroll
      for (int r = 0; r < 4; ++r) tsum[r] += __shfl_xor(tsum[r], o, 16);
#pragma unroll
    for (int r = 0; r < 4; ++r) l_run[r] = l_run[r] * alpha[r] + tsum[r];
#pragma unroll
    for (int nt = 0; nt < 4; ++nt)
#pragma unroll
      for (int r = 0; r < 4; ++r) oacc[nt][r] *= alpha[r];

    // O += P V : A-frag from Ps (m=l15=q, k=j), B-frag from Vs (n=d, k=j)
    bf16x8 pf0 = *(const bf16x8*)&psw[l15 * 64 + (((quad + 0) ^ l7) << 3)];
    bf16x8 pf1 = *(const bf16x8*)&psw[l15 * 64 + (((quad + 4) ^ l7) << 3)];
#pragma unroll
    for (int nt = 0; nt < 4; ++nt) {
      const int d = nt * 16 + l15;
      const int d7 = d & 7;
      bf16x8 vb0 = *(const bf16x8*)&Vs[d * 64 + (((quad + 0) ^ d7) << 3)];
      bf16x8 vb1 = *(const bf16x8*)&Vs[d * 64 + (((quad + 4) ^ d7) << 3)];
      oacc[nt] = __builtin_amdgcn_mfma_f32_16x16x32_bf16(pf0, vb0, oacc[nt], 0, 0, 0);
      oacc[nt] = __builtin_amdgcn_mfma_f32_16x16x32_bf16(pf1, vb1, oacc[nt], 0, 0, 0);
    }
  }

  float rl[4];
#pragma unroll
  for (int r = 0; r < 4; ++r) rl[r] = 1.0f / l_run[r];
#pragma unroll
  for (int nt = 0; nt < 4; ++nt)
#pragma unroll
    for (int r = 0; r < 4; ++r) {
      const int row = qbase + wave * 16 + quad * 4 + r;
      const int col = h * DKH + nt * 16 + l15;
      O[(size_t)(b * SEQ + row) * D_MODEL + col] = f2b(oacc[nt][r] * rl[r]);
    }
}

// ---------- row S-1 fixup: reference's fully-masked row => uniform 1/S over ALL keys ----------
__global__ __launch_bounds__(256) void vmean1_kernel(
    const u16* __restrict__ Vb, float* __restrict__ pm)
{
  const int b = blockIdx.y, slab = blockIdx.x;  // 16 slabs x 64 rows
  const int tid = threadIdx.x;
  float s0 = 0.f, s1 = 0.f;
  const size_t base = ((size_t)b * SEQ + slab * 64) * D_MODEL;
#pragma unroll 4
  for (int j = 0; j < 64; ++j) {
    s0 += b2f(Vb[base + (size_t)j * D_MODEL + tid]);
    s1 += b2f(Vb[base + (size_t)j * D_MODEL + tid + 256]);
  }
  pm[(size_t)(b * 16 + slab) * D_MODEL + tid] = s0;
  pm[(size_t)(b * 16 + slab) * D_MODEL + tid + 256] = s1;
}

__global__ __launch_bounds__(256) void vmean2_kernel(
    const float* __restrict__ pm, u16* __restrict__ O)
{
  const int b = blockIdx.x, tid = threadIdx.x;
  float s0 = 0.f, s1 = 0.f;
#pragma unroll
  for (int k = 0; k < 16; ++k) {
    s0 += pm[(size_t)(b * 16 + k) * D_MODEL + tid];
    s1 += pm[(size_t)(b * 16 + k) * D_MODEL + tid + 256];
  }
  O[(size_t)(b * SEQ + SEQ - 1) * D_MODEL + tid] = f2b(s0 * (1.f / SEQ));
  O[(size_t)(b * SEQ + SEQ - 1) * D_MODEL + tid + 256] = f2b(s1 * (1.f / SEQ));
}

// ---------- fused residual add + LayerNorm; writes f32 (residual) + bf16 (GEMM input) ----------
__global__ __launch_bounds__(256) void add_ln_kernel(
    const float* __restrict__ Hin, const float* __restrict__ T,
    const float* __restrict__ g, const float* __restrict__ bta,
    float* __restrict__ Hout, u16* __restrict__ Hb)
{
  __shared__ float red[8];
  const int row = blockIdx.x, tid = threadIdx.x;
  const int wave = tid >> 6, lane = tid & 63;
  const size_t base = (size_t)row * D_MODEL;
  const float x0 = Hin[base + tid] + T[base + tid];
  const float x1 = Hin[base + tid + 256] + T[base + tid + 256];
  float s = x0 + x1;
#pragma unroll
  for (int o = 32; o > 0; o >>= 1) s += __shfl_xor(s, o, 64);
  if (lane == 0) red[wave] = s;
  __syncthreads();
  const float mu = (red[0] + red[1] + red[2] + red[3]) * (1.f / 512.f);
  const float d0 = x0 - mu, d1 = x1 - mu;
  float v = d0 * d0 + d1 * d1;
#pragma unroll
  for (int o = 32; o > 0; o >>= 1) v += __shfl_xor(v, o, 64);
  if (lane == 0) red[4 + wave] = v;
  __syncthreads();
  const float var = (red[4] + red[5] + red[6] + red[7]) * (1.f / 512.f);
  const float rs = rsqrtf(var + 1e-5f);
  const float y0 = d0 * rs * g[tid] + bta[tid];
  const float y1 = d1 * rs * g[tid + 256] + bta[tid + 256];
  Hout[base + tid] = y0;
  Hout[base + tid + 256] = y1;
  Hb[base + tid] = f2b(y0);
  Hb[base + tid + 256] = f2b(y1);
}

extern "C" void kernel_launch(void* const* d_in, const int* in_sizes, int n_in,
                              void* d_out, int out_size, void* d_ws, size_t ws_size,
                              hipStream_t stream) {
  (void)in_sizes; (void)n_in; (void)out_size; (void)ws_size;
  const int*   ids  = (const int*)  d_in[0];
  const float* emb  = (const float*)d_in[1];
  const float* pe   = (const float*)d_in[2];
  const float* Wq   = (const float*)d_in[3];
  const float* bq   = (const float*)d_in[4];
  const float* Wk   = (const float*)d_in[5];
  const float* bk   = (const float*)d_in[6];
  const float* Wv   = (const float*)d_in[7];
  const float* bv   = (const float*)d_in[8];
  const float* Wo   = (const float*)d_in[9];
  const float* bo   = (const float*)d_in[10];
  const float* g1   = (const float*)d_in[11];
  const float* be1  = (const float*)d_in[12];
  const float* W1   = (const float*)d_in[13];
  const float* b1   = (const float*)d_in[14];
  const float* W2   = (const float*)d_in[15];
  const float* b2   = (const float*)d_in[16];
  const float* g2   = (const float*)d_in[17];
  const float* be2  = (const float*)d_in[18];
  const float* Wout = (const float*)d_in[19];
  const float* bout = (const float*)d_in[20];
  float* out = (float*)d_out;

  char* wsp = (char*)d_ws;
  auto alloc = [&](size_t bytes) -> char* {
    char* p = wsp; wsp += (bytes + 255) & ~(size_t)255; return p;
  };
  const size_t dd = (size_t)D_MODEL * D_MODEL;          // 262144
  const size_t df = (size_t)D_MODEL * FFN;              // 1048576
  u16* wq_t  = (u16*)alloc(NLAYER * dd * 2);
  u16* wk_t  = (u16*)alloc(NLAYER * dd * 2);
  u16* wv_t  = (u16*)alloc(NLAYER * dd * 2);
  u16* wo_t  = (u16*)alloc(NLAYER * dd * 2);
  u16* w1_t  = (u16*)alloc(NLAYER * df * 2);
  u16* w2_t  = (u16*)alloc(NLAYER * df * 2);
  u16* wout_t= (u16*)alloc(dd * 2);
  float* hf  = (float*)alloc((size_t)MROWS * D_MODEL * 4);
  u16*   hb  = (u16*)  alloc((size_t)MROWS * D_MODEL * 2);
  u16*   qb  = (u16*)  alloc((size_t)MROWS * D_MODEL * 2);
  u16*   kb  = (u16*)  alloc((size_t)MROWS * D_MODEL * 2);
  u16*   vb  = (u16*)  alloc((size_t)MROWS * D_MODEL * 2);
  u16*   ob  = (u16*)  alloc((size_t)MROWS * D_MODEL * 2);
  float* tf  = (float*)alloc((size_t)MROWS * D_MODEL * 4);
  float* pm  = (float*)alloc((size_t)BATCH * 16 * D_MODEL * 4);  // vmean partials
  u16*   mid = qb;  // FFN mid [8192,2048] bf16 aliases the (dead-by-then) q/k/v/o region

  dim3 tb(32, 8);
  transpose_cvt_kernel<<<dim3(16, 16, NLAYER), tb, 0, stream>>>(Wq, wq_t, 512, 512);
  transpose_cvt_kernel<<<dim3(16, 16, NLAYER), tb, 0, stream>>>(Wk, wk_t, 512, 512);
  transpose_cvt_kernel<<<dim3(16, 16, NLAYER), tb, 0, stream>>>(Wv, wv_t, 512, 512);
  transpose_cvt_kernel<<<dim3(16, 16, NLAYER), tb, 0, stream>>>(Wo, wo_t, 512, 512);
  transpose_cvt_kernel<<<dim3(64, 16, NLAYER), tb, 0, stream>>>(W1, w1_t, 512, 2048);
  transpose_cvt_kernel<<<dim3(16, 64, NLAYER), tb, 0, stream>>>(W2, w2_t, 2048, 512);
  transpose_cvt_kernel<<<dim3(16, 16, 1),      tb, 0, stream>>>(Wout, wout_t, 512, 512);

  embed_kernel<<<MROWS, 256, 0, stream>>>(ids, emb, pe, hf, hb);

  for (int l = 0; l < NLAYER; ++l) {
    gemm_kernel<false, false, true><<<dim3(64, 4), 256, 0, stream>>>(
        hb, wq_t + l * dd, bq + l * 512, nullptr, qb, MROWS, 512, 512);
    gemm_kernel<false, false, true><<<dim3(64, 4), 256, 0, stream>>>(
        hb, wk_t + l * dd, bk + l * 512, nullptr, kb, MROWS, 512, 512);
    gemm_kernel<false, false, true><<<dim3(64, 4), 256, 0, stream>>>(
        hb, wv_t + l * dd, bv + l * 512, nullptr, vb, MROWS, 512, 512);
    attn_mfma_kernel<<<dim3(SEQ / 64, NHEAD, BATCH), 256, 0, stream>>>(qb, kb, vb, ob);
    vmean1_kernel<<<dim3(16, BATCH), 256, 0, stream>>>(vb, pm);
    vmean2_kernel<<<BATCH, 256, 0, stream>>>(pm, ob);
    gemm_kernel<false, true, false><<<dim3(64, 4), 256, 0, stream>>>(
        ob, wo_t + l * dd, bo + l * 512, tf, nullptr, MROWS, 512, 512);
    add_ln_kernel<<<MROWS, 256, 0, stream>>>(hf, tf, g1 + l * 512, be1 + l * 512, hf, hb);
    gemm_kernel<true, false, true><<<dim3(64, 16), 256, 0, stream>>>(
        hb, w1_t + l * df, b1 + l * 2048, nullptr, mid, MROWS, 2048, 512);
    gemm_kernel<false, true, false><<<dim3(64, 4), 256, 0, stream>>>(
        mid, w2_t + l * df, b2 + l * 512, tf, nullptr, MROWS, 512, 2048);
    add_ln_kernel<<<MROWS, 256, 0, stream>>>(hf, tf, g2 + l * 512, be2 + l * 512, hf, hb);
  }
  gemm_kernel<false, true, false><<<dim3(64, 4), 256, 0, stream>>>(
      hb, wout_t, bout, out, nullptr, MROWS, 512, 512);
}

// Round 3
// 1438.163 us; speedup vs baseline: 3.4614x; 1.0490x over previous
//
#include <hip/hip_runtime.h>

typedef unsigned short u16;
typedef __attribute__((ext_vector_type(8))) short bf16x8;   // 8 bf16 (4 VGPRs)
typedef __attribute__((ext_vector_type(4))) float f32x4;
typedef __attribute__((ext_vector_type(4))) unsigned int uint4v;

#define NLAYER 6
#define D_MODEL 512
#define NHEAD 8
#define DKH 64
#define SEQ 1024
#define BATCH 8
#define FFN 2048
#define MROWS (BATCH * SEQ)  /* 8192 */
#define QKV_LD 1536
#define SCALE_LOG2E 0.18033688011112042f  /* (1/sqrt(64)) * log2(e) */

__device__ __forceinline__ float b2f(u16 u) {
  union { unsigned u32; float f; } x; x.u32 = ((unsigned)u) << 16; return x.f;
}
__device__ __forceinline__ u16 f2b(float f) {
  union { float f; unsigned u; } x; x.f = f;
  unsigned r = x.u + 0x7FFFu + ((x.u >> 16) & 1u);   // RNE
  return (u16)(r >> 16);
}
// async global->LDS, 16B per lane; LDS dest = wave-uniform base + lane*16 (m97)
__device__ __forceinline__ void gld16(const u16* g, u16* l) {
  __builtin_amdgcn_global_load_lds(
      (const __attribute__((address_space(1))) unsigned int*)g,
      (__attribute__((address_space(3))) unsigned int*)l, 16, 0, 0);
}

// ---------- weight transpose + f32->bf16 : src [Z][K][N] f32 -> dst [Z][N][K] bf16 ----------
__global__ __launch_bounds__(256) void transpose_cvt_kernel(
    const float* __restrict__ src, u16* __restrict__ dst, int K, int N, size_t dstZ)
{
  __shared__ float t[32][33];
  const int z = blockIdx.z;
  src += (size_t)z * K * N;
  dst += (size_t)z * dstZ;
  const int n0 = blockIdx.x * 32, k0 = blockIdx.y * 32;
  const int tx = threadIdx.x, ty = threadIdx.y;  // 32 x 8
#pragma unroll
  for (int i = 0; i < 32; i += 8)
    t[ty + i][tx] = src[(size_t)(k0 + ty + i) * N + n0 + tx];
  __syncthreads();
#pragma unroll
  for (int i = 0; i < 32; i += 8)
    dst[(size_t)(n0 + ty + i) * K + k0 + tx] = f2b(t[tx][ty + i]);
}

// ---------- concat per-layer q/k/v biases into [L][1536] ----------
__global__ __launch_bounds__(256) void concat_bias_kernel(
    const float* __restrict__ bq, const float* __restrict__ bk,
    const float* __restrict__ bv, float* __restrict__ dst)
{
  const int l = blockIdx.x, t = threadIdx.x;
#pragma unroll
  for (int j = t; j < 512; j += 256) {
    dst[l * QKV_LD + j]        = bq[l * 512 + j];
    dst[l * QKV_LD + 512 + j]  = bk[l * 512 + j];
    dst[l * QKV_LD + 1024 + j] = bv[l * 512 + j];
  }
}

// ---------- embedding: h = emb[ids]*sqrt(D) + pe[s] ----------
__global__ __launch_bounds__(256) void embed_kernel(
    const int* __restrict__ ids, const float* __restrict__ emb,
    const float* __restrict__ pe, float* __restrict__ Hf, u16* __restrict__ Hb)
{
  const int row = blockIdx.x;
  const int s = row & (SEQ - 1);
  const int id = ids[row];
  const int tid = threadIdx.x;
#pragma unroll
  for (int u = 0; u < 2; ++u) {
    const int d = tid + u * 256;
    float v = emb[(size_t)id * D_MODEL + d] * 22.62741699796952f + pe[(size_t)s * D_MODEL + d];
    Hf[(size_t)row * D_MODEL + d] = v;
    Hb[(size_t)row * D_MODEL + d] = f2b(v);
  }
}

// ---------- bf16 MFMA GEMM: C[M,N] = A[M,K] @ Bt[N,K]^T + bias ----------
// BMTx128 tile, BK=32, global_load_lds(16B) staging (m97 pattern).
template<int BMT, bool RELU, bool OUTF, bool OUTB>
__global__ __launch_bounds__(256) void gemm_kernel(
    const u16* __restrict__ A, const u16* __restrict__ Bt,
    const float* __restrict__ bias,
    float* __restrict__ Cf, u16* __restrict__ Cb,
    int M, int N, int K)
{
  constexpr int IT = BMT / 32;                      // 4 (BMT=128) or 2 (BMT=64)
  __shared__ __align__(16) u16 As[BMT * 32];
  __shared__ __align__(16) u16 Bs[128 * 32];
  const int tid = threadIdx.x;
  const int bm = blockIdx.x * BMT, bn = blockIdx.y * 128;
  const int wave = tid >> 6, lane = tid & 63;
  const int lm = lane & 15, quad = lane >> 4;
  const int wm = (wave & 1) * (BMT / 2), wn = (wave >> 1) * 64;
  const int r0 = tid >> 2;            // 0..63
  const int c0 = (tid & 3) * 8;       // 0,8,16,24

  const u16* Ap = A  + (size_t)(bm + r0) * K + c0;
  const u16* Bp = Bt + (size_t)(bn + r0) * K + c0;
  // LDS layout: byte offset == tid*16 for chunk 0 (lane-linear, required by gld)
  u16* lA  = As + wave * 512;
  u16* lA2 = lA + 64 * 32;
  u16* lB  = Bs + wave * 512;
  u16* lB2 = lB + 64 * 32;

  f32x4 acc[IT][4] = {};

  for (int kk = 0; kk < K; kk += 32) {
    __syncthreads();                  // prior iter's frag reads done
    gld16(Ap + kk, lA);
    if (BMT == 128) gld16(Ap + kk + (size_t)64 * K, lA2);
    gld16(Bp + kk, lB);
    gld16(Bp + kk + (size_t)64 * K, lB2);
    __syncthreads();                  // compiler emits vmcnt(0) drain before barrier
    bf16x8 af[IT], bg[4];
#pragma unroll
    for (int i = 0; i < IT; ++i)
      af[i] = *(const bf16x8*)&As[(wm + i * 16 + lm) * 32 + quad * 8];
#pragma unroll
    for (int j = 0; j < 4; ++j)
      bg[j] = *(const bf16x8*)&Bs[(wn + j * 16 + lm) * 32 + quad * 8];
#pragma unroll
    for (int i = 0; i < IT; ++i)
#pragma unroll
      for (int j = 0; j < 4; ++j)
        acc[i][j] = __builtin_amdgcn_mfma_f32_16x16x32_bf16(af[i], bg[j], acc[i][j], 0, 0, 0);
  }

  // epilogue: D row = quad*4+reg, col = lm
  const int mbase = bm + wm + quad * 4;
  const int nbase = bn + wn + lm;
#pragma unroll
  for (int i = 0; i < IT; ++i) {
#pragma unroll
    for (int j = 0; j < 4; ++j) {
      const int n = nbase + j * 16;
      const float bv = bias[n];
#pragma unroll
      for (int r = 0; r < 4; ++r) {
        const int m = mbase + i * 16 + r;
        float v = acc[i][j][r] + bv;
        if (RELU) v = fmaxf(v, 0.f);
        if (OUTF) Cf[(size_t)m * N + n] = v;
        if (OUTB) Cb[(size_t)m * N + n] = f2b(v);
      }
    }
  }
}

// ---------- V^T: qkv[:, 1024+h*64+d] -> vt[bh][d][s] (bf16) ----------
__global__ __launch_bounds__(256) void vt_kernel(
    const u16* __restrict__ QKV, u16* __restrict__ Vt)
{
  __shared__ __align__(16) u16 t[64 * 72];          // stride 72: 144B rows (16B-aligned)
  const int bh = blockIdx.y, s0 = blockIdx.x * 64;
  const int b = bh >> 3, h = bh & 7;
  const int tid = threadIdx.x;
#pragma unroll
  for (int pass = 0; pass < 2; ++pass) {
    const int s = (tid >> 3) + pass * 32, dc = (tid & 7) * 8;
    uint4v w = *(const uint4v*)(QKV + ((size_t)(b * SEQ) + s0 + s) * QKV_LD + 1024 + h * 64 + dc);
    *(uint4v*)&t[s * 72 + dc] = w;
  }
  __syncthreads();
#pragma unroll
  for (int pass = 0; pass < 2; ++pass) {
    const int d = (tid >> 3) + pass * 32, sc = (tid & 7) * 8;
    uint4v o;
#pragma unroll
    for (int q = 0; q < 4; ++q) {
      const unsigned lo = t[(sc + 2 * q) * 72 + d];
      const unsigned hi = t[(sc + 2 * q + 1) * 72 + d];
      o[q] = lo | (hi << 16);
    }
    *(uint4v*)&Vt[((size_t)bh * 64 + d) * SEQ + s0 + sc] = o;
  }
}

// ---------- barrier-free MFMA flash attention, anti-causal mask (keep j > i) ----------
// wave = 16 q-rows; processes q-units p and 63-p (uniform 17 tile-steps/wave).
// K frags direct from QKV (col 512+), V frags direct from Vt; P via per-wave LDS.
__global__ __launch_bounds__(256) void attn_mfma_kernel(
    const u16* __restrict__ QKV, const u16* __restrict__ Vt, u16* __restrict__ O)
{
  __shared__ __align__(16) u16 Ps[4 * 16 * 64];
  const int tid = threadIdx.x;
  const int wave = tid >> 6, lane = tid & 63;
  const int quad = lane >> 4, l15 = lane & 15;
  const int b = blockIdx.z, h = blockIdx.y;
  const int p = blockIdx.x * 4 + wave;              // 0..31
  u16* psw = Ps + wave * (16 * 64);
  const size_t qoff = (size_t)b * SEQ * QKV_LD + h * 64;
  const size_t koff = qoff + 512;
  const size_t vtb = (size_t)(b * NHEAD + h) * 64 * SEQ;

  for (int half = 0; half < 2; ++half) {
    const int u = half ? (63 - p) : p;              // 16-row q-unit
    const int jt0 = u >> 2;
    const u16* qp = QKV + qoff + (size_t)(u * 16 + l15) * QKV_LD + quad * 8;
    const bf16x8 qf0 = *(const bf16x8*)qp;
    const bf16x8 qf1 = *(const bf16x8*)(qp + 32);

    f32x4 oacc[4] = {};
    float m_run[4], l_run[4];
#pragma unroll
    for (int r = 0; r < 4; ++r) { m_run[r] = -3.0e38f; l_run[r] = 0.f; }

    for (int jt = jt0; jt < SEQ / 64; ++jt) {
      bf16x8 kf0[4], kf1[4], vf0[4], vf1[4];
#pragma unroll
      for (int nt = 0; nt < 4; ++nt) {
        const u16* kp = QKV + koff + (size_t)(jt * 64 + nt * 16 + l15) * QKV_LD + quad * 8;
        kf0[nt] = *(const bf16x8*)kp;
        kf1[nt] = *(const bf16x8*)(kp + 32);
        const u16* vp = Vt + vtb + (size_t)(nt * 16 + l15) * SEQ + jt * 64 + quad * 8;
        vf0[nt] = *(const bf16x8*)vp;               // used only after softmax:
        vf1[nt] = *(const bf16x8*)(vp + 32);        // latency hidden by VALU below
      }
      f32x4 sacc[4] = {};
#pragma unroll
      for (int nt = 0; nt < 4; ++nt) {
        sacc[nt] = __builtin_amdgcn_mfma_f32_16x16x32_bf16(qf0, kf0[nt], sacc[nt], 0, 0, 0);
        sacc[nt] = __builtin_amdgcn_mfma_f32_16x16x32_bf16(qf1, kf1[nt], sacc[nt], 0, 0, 0);
      }
      // scale into exp2 domain + mask (diagonal tile only; uniform branch)
      if (jt == jt0) {
#pragma unroll
        for (int nt = 0; nt < 4; ++nt)
#pragma unroll
          for (int r = 0; r < 4; ++r) {
            const int i = u * 16 + quad * 4 + r;
            const int j = jt * 64 + nt * 16 + l15;
            sacc[nt][r] = (j > i) ? sacc[nt][r] * SCALE_LOG2E : -3.0e38f;
          }
      } else {
#pragma unroll
        for (int nt = 0; nt < 4; ++nt)
#pragma unroll
          for (int r = 0; r < 4; ++r) sacc[nt][r] *= SCALE_LOG2E;
      }
      // online softmax per D-row (quad-group of 16 lanes)
      float tmax[4];
#pragma unroll
      for (int r = 0; r < 4; ++r)
        tmax[r] = fmaxf(fmaxf(sacc[0][r], sacc[1][r]), fmaxf(sacc[2][r], sacc[3][r]));
#pragma unroll
      for (int o = 1; o < 16; o <<= 1)
#pragma unroll
        for (int r = 0; r < 4; ++r) tmax[r] = fmaxf(tmax[r], __shfl_xor(tmax[r], o, 16));
      float alpha[4], m_new[4], tsum[4];
#pragma unroll
      for (int r = 0; r < 4; ++r) {
        m_new[r] = fmaxf(m_run[r], tmax[r]);
        alpha[r] = exp2f(m_run[r] - m_new[r]);
        m_run[r] = m_new[r];
        tsum[r] = 0.f;
      }
#pragma unroll
      for (int nt = 0; nt < 4; ++nt)
#pragma unroll
        for (int r = 0; r < 4; ++r) {
          const float pv = exp2f(sacc[nt][r] - m_new[r]);  // fully-masked tile => pv=1,
          tsum[r] += pv;                                   // annihilated later by alpha=0
          const int qr = quad * 4 + r;
          const int j = nt * 16 + l15;
          psw[qr * 64 + (((j >> 3) ^ (qr & 7)) << 3) + (j & 7)] = f2b(pv);
        }
#pragma unroll
      for (int o = 1; o < 16; o <<= 1)
#pragma unroll
        for (int r = 0; r < 4; ++r) tsum[r] += __shfl_xor(tsum[r], o, 16);
#pragma unroll
      for (int r = 0; r < 4; ++r) l_run[r] = l_run[r] * alpha[r] + tsum[r];
#pragma unroll
      for (int nt = 0; nt < 4; ++nt)
#pragma unroll
        for (int r = 0; r < 4; ++r) oacc[nt][r] *= alpha[r];
      // P A-frag from per-wave LDS (no barrier: same-wave write->read)
      const int l7 = l15 & 7;
      bf16x8 pf0 = *(const bf16x8*)&psw[l15 * 64 + (((quad + 0) ^ l7) << 3)];
      bf16x8 pf1 = *(const bf16x8*)&psw[l15 * 64 + (((quad + 4) ^ l7) << 3)];
#pragma unroll
      for (int nt = 0; nt < 4; ++nt) {
        oacc[nt] = __builtin_amdgcn_mfma_f32_16x16x32_bf16(pf0, vf0[nt], oacc[nt], 0, 0, 0);
        oacc[nt] = __builtin_amdgcn_mfma_f32_16x16x32_bf16(pf1, vf1[nt], oacc[nt], 0, 0, 0);
      }
    }
    float rl[4];
#pragma unroll
    for (int r = 0; r < 4; ++r) rl[r] = 1.0f / l_run[r];
#pragma unroll
    for (int nt = 0; nt < 4; ++nt)
#pragma unroll
      for (int r = 0; r < 4; ++r) {
        const int row = u * 16 + quad * 4 + r;
        O[(size_t)(b * SEQ + row) * D_MODEL + h * DKH + nt * 16 + l15] = f2b(oacc[nt][r] * rl[r]);
      }
  }
}

// ---------- row S-1 fixup: fully-masked row => uniform mean over ALL keys ----------
__global__ __launch_bounds__(256) void vmean_kernel(
    const u16* __restrict__ Vt, u16* __restrict__ O)
{
  const int bh = blockIdx.x, tid = threadIdx.x;
  const int d = tid >> 2, sc = (tid & 3) * 256;
  const u16* p = Vt + ((size_t)bh * 64 + d) * SEQ + sc;
  float s = 0.f;
#pragma unroll 8
  for (int i = 0; i < 256; ++i) s += b2f(p[i]);
  s += __shfl_xor(s, 1, 64);
  s += __shfl_xor(s, 2, 64);
  if ((tid & 3) == 0) {
    const int b = bh >> 3, h = bh & 7;
    O[((size_t)b * SEQ + SEQ - 1) * D_MODEL + h * 64 + d] = f2b(s * (1.f / SEQ));
  }
}

// ---------- fused residual add + LayerNorm; writes f32 (residual) + bf16 (GEMM input) ----------
__global__ __launch_bounds__(256) void add_ln_kernel(
    const float* __restrict__ Hin, const float* __restrict__ T,
    const float* __restrict__ g, const float* __restrict__ bta,
    float* __restrict__ Hout, u16* __restrict__ Hb)
{
  __shared__ float red[8];
  const int row = blockIdx.x, tid = threadIdx.x;
  const int wave = tid >> 6, lane = tid & 63;
  const size_t base = (size_t)row * D_MODEL;
  const float x0 = Hin[base + tid] + T[base + tid];
  const float x1 = Hin[base + tid + 256] + T[base + tid + 256];
  float s = x0 + x1;
#pragma unroll
  for (int o = 32; o > 0; o >>= 1) s += __shfl_xor(s, o, 64);
  if (lane == 0) red[wave] = s;
  __syncthreads();
  const float mu = (red[0] + red[1] + red[2] + red[3]) * (1.f / 512.f);
  const float d0 = x0 - mu, d1 = x1 - mu;
  float v = d0 * d0 + d1 * d1;
#pragma unroll
  for (int o = 32; o > 0; o >>= 1) v += __shfl_xor(v, o, 64);
  if (lane == 0) red[4 + wave] = v;
  __syncthreads();
  const float var = (red[4] + red[5] + red[6] + red[7]) * (1.f / 512.f);
  const float rs = rsqrtf(var + 1e-5f);
  const float y0 = d0 * rs * g[tid] + bta[tid];
  const float y1 = d1 * rs * g[tid + 256] + bta[tid + 256];
  Hout[base + tid] = y0;
  Hout[base + tid + 256] = y1;
  Hb[base + tid] = f2b(y0);
  Hb[base + tid + 256] = f2b(y1);
}

extern "C" void kernel_launch(void* const* d_in, const int* in_sizes, int n_in,
                              void* d_out, int out_size, void* d_ws, size_t ws_size,
                              hipStream_t stream) {
  (void)in_sizes; (void)n_in; (void)out_size; (void)ws_size;
  const int*   ids  = (const int*)  d_in[0];
  const float* emb  = (const float*)d_in[1];
  const float* pe   = (const float*)d_in[2];
  const float* Wq   = (const float*)d_in[3];
  const float* bq   = (const float*)d_in[4];
  const float* Wk   = (const float*)d_in[5];
  const float* bk   = (const float*)d_in[6];
  const float* Wv   = (const float*)d_in[7];
  const float* bv   = (const float*)d_in[8];
  const float* Wo   = (const float*)d_in[9];
  const float* bo   = (const float*)d_in[10];
  const float* g1   = (const float*)d_in[11];
  const float* be1  = (const float*)d_in[12];
  const float* W1   = (const float*)d_in[13];
  const float* b1   = (const float*)d_in[14];
  const float* W2   = (const float*)d_in[15];
  const float* b2   = (const float*)d_in[16];
  const float* g2   = (const float*)d_in[17];
  const float* be2  = (const float*)d_in[18];
  const float* Wout = (const float*)d_in[19];
  const float* bout = (const float*)d_in[20];
  float* out = (float*)d_out;

  char* wsp = (char*)d_ws;
  auto alloc = [&](size_t bytes) -> char* {
    char* p = wsp; wsp += (bytes + 255) & ~(size_t)255; return p;
  };
  const size_t dd  = (size_t)D_MODEL * D_MODEL;      // 262144
  const size_t df  = (size_t)D_MODEL * FFN;          // 1048576
  const size_t dq  = (size_t)QKV_LD * D_MODEL;       // 786432
  u16* wqkv_t = (u16*)alloc(NLAYER * dq * 2);
  u16* wo_t   = (u16*)alloc(NLAYER * dd * 2);
  u16* w1_t   = (u16*)alloc(NLAYER * df * 2);
  u16* w2_t   = (u16*)alloc(NLAYER * df * 2);
  u16* wout_t = (u16*)alloc(dd * 2);
  float* bqkv = (float*)alloc(NLAYER * QKV_LD * 4);
  float* hf   = (float*)alloc((size_t)MROWS * D_MODEL * 4);
  u16*   hb   = (u16*)  alloc((size_t)MROWS * D_MODEL * 2);
  u16*   qkvb = (u16*)  alloc((size_t)MROWS * QKV_LD * 2);   // 24 MB
  u16*   ob   = (u16*)  alloc((size_t)MROWS * D_MODEL * 2);  // 8 MB, right after qkvb
  u16*   vt   = (u16*)  alloc((size_t)BATCH * NHEAD * DKH * SEQ * 2);
  float* tf   = (float*)alloc((size_t)MROWS * D_MODEL * 4);
  u16*   mid  = qkvb;  // FFN mid [8192,2048] aliases qkvb+ob (dead by FFN1; stream-ordered)

  dim3 tb(32, 8);
  transpose_cvt_kernel<<<dim3(16, 16, NLAYER), tb, 0, stream>>>(Wq, wqkv_t,            512, 512,  dq);
  transpose_cvt_kernel<<<dim3(16, 16, NLAYER), tb, 0, stream>>>(Wk, wqkv_t + 512*512,  512, 512,  dq);
  transpose_cvt_kernel<<<dim3(16, 16, NLAYER), tb, 0, stream>>>(Wv, wqkv_t + 1024*512, 512, 512,  dq);
  transpose_cvt_kernel<<<dim3(16, 16, NLAYER), tb, 0, stream>>>(Wo, wo_t,   512, 512,  dd);
  transpose_cvt_kernel<<<dim3(64, 16, NLAYER), tb, 0, stream>>>(W1, w1_t,   512, 2048, df);
  transpose_cvt_kernel<<<dim3(16, 64, NLAYER), tb, 0, stream>>>(W2, w2_t,   2048, 512, df);
  transpose_cvt_kernel<<<dim3(16, 16, 1),      tb, 0, stream>>>(Wout, wout_t, 512, 512, dd);
  concat_bias_kernel<<<NLAYER, 256, 0, stream>>>(bq, bk, bv, bqkv);

  embed_kernel<<<MROWS, 256, 0, stream>>>(ids, emb, pe, hf, hb);

  for (int l = 0; l < NLAYER; ++l) {
    gemm_kernel<128, false, false, true><<<dim3(64, 12), 256, 0, stream>>>(
        hb, wqkv_t + l * dq, bqkv + l * QKV_LD, nullptr, qkvb, MROWS, QKV_LD, 512);
    vt_kernel<<<dim3(16, 64), 256, 0, stream>>>(qkvb, vt);
    attn_mfma_kernel<<<dim3(8, NHEAD, BATCH), 256, 0, stream>>>(qkvb, vt, ob);
    vmean_kernel<<<64, 256, 0, stream>>>(vt, ob);
    gemm_kernel<64, false, true, false><<<dim3(128, 4), 256, 0, stream>>>(
        ob, wo_t + l * dd, bo + l * 512, tf, nullptr, MROWS, 512, 512);
    add_ln_kernel<<<MROWS, 256, 0, stream>>>(hf, tf, g1 + l * 512, be1 + l * 512, hf, hb);
    gemm_kernel<128, true, false, true><<<dim3(64, 16), 256, 0, stream>>>(
        hb, w1_t + l * df, b1 + l * 2048, nullptr, mid, MROWS, 2048, 512);
    gemm_kernel<64, false, true, false><<<dim3(128, 4), 256, 0, stream>>>(
        mid, w2_t + l * df, b2 + l * 512, tf, nullptr, MROWS, 512, 2048);
    add_ln_kernel<<<MROWS, 256, 0, stream>>>(hf, tf, g2 + l * 512, be2 + l * 512, hf, hb);
  }
  gemm_kernel<64, false, true, false><<<dim3(128, 4), 256, 0, stream>>>(
      hb, wout_t, bout, out, nullptr, MROWS, 512, 512);
}